// Round 12
// baseline (129.697 us; speedup 1.0000x reference)
//
#include <hip/hip_runtime.h>
#include <math.h>

#define D_ 96
#define L_ 4096
#define K_ 8
#define N_ 16
#define R_ 6
#define CDBL 38   // R + 2N
#define DL_ (D_ * L_)

#define REP8(M) M(0) M(1) M(2) M(3) M(4) M(5) M(6) M(7)
#define FENCE asm volatile("" ::: "memory");

#if __has_builtin(__builtin_amdgcn_exp2f)
#define EXP2(x) __builtin_amdgcn_exp2f(x)
#else
#define EXP2(x) exp2f(x)
#endif
#if __has_builtin(__builtin_amdgcn_logf)
#define LOG2F(x) __builtin_amdgcn_logf(x)
#else
#define LOG2F(x) __log2f(x)
#endif

#define LOG2E 1.44269504088896340736f
#define LN2F  0.69314718055994530942f

// source index within one channel's [64][64] image for direction k, flat pos l
__device__ __forceinline__ int src_index(int k, int l) {
    int h = l & 63, w = l >> 6;
    int lp = 4095 - l;
    int hp = lp & 63, wp = lp >> 6;
    switch (k) {
    case 0: return l;
    case 1: return (h << 6) + w;
    case 2: return lp;
    case 3: return (hp << 6) + wp;
    case 4: return (h << 6) + ((h + w) & 63);
    case 5: return (h << 6) + ((w - h) & 63);
    case 6: return (hp << 6) + ((hp + wp) & 63);
    default: return (hp << 6) + ((wp - hp) & 63);
    }
}

// inverse-permutation source for cross_merge (h = l>>6, w = l&63)
__device__ __forceinline__ int merge_src(int k, int l) {
    int h = l >> 6, w = l & 63;
    int i1 = (w << 6) + h;
    int i4 = (((w - h) & 63) << 6) + h;
    int i5 = (((w + h) & 63) << 6) + h;
    switch (k) {
    case 0: return l;
    case 1: return i1;
    case 2: return 4095 - l;
    case 3: return 4095 - i1;
    case 4: return i4;
    case 5: return i5;
    case 6: return 4095 - i4;
    default: return 4095 - i5;
    }
}

// padded LDS address for a [64][64] image tile (pad 66)
#define PQ(p) ((((p) >> 6) * 66) + ((p) & 63))

// ---------------- K0: cross-scan materialization x -> xs[8][96][4096] --------
__global__ __launch_bounds__(512) void k_xscan(const float* __restrict__ x,
                                               float* __restrict__ xs) {
    __shared__ float img[64 * 66];
    int d = blockIdx.x;
    int t = threadIdx.x;
    const float* xd = x + d * L_;
    #pragma unroll
    for (int i = 0; i < 8; ++i) {
        int l = i * 512 + t;
        img[PQ(l)] = xd[l];
    }
    __syncthreads();
    #pragma unroll
    for (int k = 0; k < K_; ++k) {
        float* dst = xs + (k * D_ + d) * L_;
        #pragma unroll
        for (int i = 0; i < 8; ++i) {
            int l = i * 512 + t;
            dst[l] = img[PQ(src_index(k, l))];
        }
    }
}

// ---------------- K1: x_dbl = wproj @ xs  (all-coalesced) --------------------
__global__ __launch_bounds__(256) void k_xdbl(const float* __restrict__ xs,
                                              const float* __restrict__ wproj,
                                              float* __restrict__ xdbl) {
    __shared__ float tile[64][100];
    int bid = blockIdx.x;
    int swz = (bid & 7) * 64 + (bid >> 3);   // XCD swizzle: each XCD owns one k
    int k = swz >> 6;
    int l0 = (swz & 63) * 64;

    const float* src = xs + k * DL_ + l0;
    for (int e = threadIdx.x; e < D_ * 64; e += 256) {
        int d = e >> 6, li = e & 63;
        tile[li][d] = src[d * L_ + li];     // coalesced
    }
    __syncthreads();

    int lt = threadIdx.x & 63;
    int cg = __builtin_amdgcn_readfirstlane(threadIdx.x >> 6);   // wave-uniform 0..3
    const float* wk = wproj + k * CDBL * D_;
    float acc[10];
    #pragma unroll
    for (int j = 0; j < 10; ++j) acc[j] = 0.f;
    for (int d4 = 0; d4 < D_; d4 += 4) {
        float4 tv = *(const float4*)&tile[lt][d4];
        #pragma unroll
        for (int j = 0; j < 10; ++j) {
            int c = cg + 4 * j;
            if (c < CDBL) {
                float4 wv = *(const float4*)&wk[c * D_ + d4];   // scalar -> s_load
                acc[j] = fmaf(tv.x, wv.x, acc[j]);
                acc[j] = fmaf(tv.y, wv.y, acc[j]);
                acc[j] = fmaf(tv.z, wv.z, acc[j]);
                acc[j] = fmaf(tv.w, wv.w, acc[j]);
            }
        }
    }
    #pragma unroll
    for (int j = 0; j < 10; ++j) {
        int c = cg + 4 * j;
        if (c < CDBL) xdbl[(k * CDBL + c) * L_ + l0 + lt] = acc[j];
    }
}

// ---------------- K2a: delta precompute (log2 domain) ------------------------
// grid 768 (kd, k == XCD id), block 512, 8 l/thread. Hoisted out of k_scan so
// the scan kernel fits the 64-VGPR tier (r11 lesson: delta machinery is
// exactly the ~8-reg overage that forced 72 VGPR -> 16 waves/CU tier).
__global__ __launch_bounds__(512) void k_delta(const float* __restrict__ xdbl,
                                               const float* __restrict__ dtw,
                                               const float* __restrict__ dtb,
                                               float* __restrict__ dlt) {
    int bid = blockIdx.x;
    int k = bid & 7;
    int d = bid >> 3;
    int kd = k * D_ + d;
    int l0t = threadIdx.x * 8;

    const float* xr = xdbl + k * CDBL * L_;
    const float2* wp2 = (const float2*)(dtw + kd * R_);
    const float2 w01 = wp2[0], w23 = wp2[1], w45 = wp2[2];
    const float bias = dtb[kd];
    float d0, d1, d2, d3, d4, d5, d6, d7;
#define SPL2(dst, s) { float p = (s) * LOG2E; \
    float l2 = LOG2F(1.f + EXP2(p)); \
    dst = ((s) > 20.f) ? p : l2; }
#define DLTQ(j, i0, i1, i2, i3) { \
    const float4 r0 = *(const float4*)(xr + 0 * L_ + l0t + j * 4); \
    const float4 r1 = *(const float4*)(xr + 1 * L_ + l0t + j * 4); \
    const float4 r2 = *(const float4*)(xr + 2 * L_ + l0t + j * 4); \
    const float4 r3 = *(const float4*)(xr + 3 * L_ + l0t + j * 4); \
    const float4 r4 = *(const float4*)(xr + 4 * L_ + l0t + j * 4); \
    const float4 r5 = *(const float4*)(xr + 5 * L_ + l0t + j * 4); \
    float s; \
    s = fmaf(w01.x, r0.x, bias); s = fmaf(w01.y, r1.x, s); s = fmaf(w23.x, r2.x, s); \
    s = fmaf(w23.y, r3.x, s); s = fmaf(w45.x, r4.x, s); s = fmaf(w45.y, r5.x, s); \
    SPL2(d##i0, s) \
    s = fmaf(w01.x, r0.y, bias); s = fmaf(w01.y, r1.y, s); s = fmaf(w23.x, r2.y, s); \
    s = fmaf(w23.y, r3.y, s); s = fmaf(w45.x, r4.y, s); s = fmaf(w45.y, r5.y, s); \
    SPL2(d##i1, s) \
    s = fmaf(w01.x, r0.z, bias); s = fmaf(w01.y, r1.z, s); s = fmaf(w23.x, r2.z, s); \
    s = fmaf(w23.y, r3.z, s); s = fmaf(w45.x, r4.z, s); s = fmaf(w45.y, r5.z, s); \
    SPL2(d##i2, s) \
    s = fmaf(w01.x, r0.w, bias); s = fmaf(w01.y, r1.w, s); s = fmaf(w23.x, r2.w, s); \
    s = fmaf(w23.y, r3.w, s); s = fmaf(w45.x, r4.w, s); s = fmaf(w45.y, r5.w, s); \
    SPL2(d##i3, s) }
    DLTQ(0, 0, 1, 2, 3)
    DLTQ(1, 4, 5, 6, 7)
#undef DLTQ
#undef SPL2
    float* dp = dlt + kd * L_ + l0t;
    float4 o;
    o.x = d0; o.y = d1; o.z = d2; o.w = d3; *(float4*)(dp + 0) = o;
    o.x = d4; o.y = d5; o.z = d6; o.w = d7; *(float4*)(dp + 4) = o;
}

// ---------------- K2b: selective scan (two n-groups, no inline delta) --------
// 512 threads, 8 elem/thread, grid 768. Two sequential groups of 8 n-states
// -> scan state is 16 regs; with delta hoisted out, total live ~58 regs ->
// __launch_bounds__(512,4) cap 64 -> 32 waves/CU tier -> grid 768 = 3
// blocks/CU FULLY RESIDENT in the 4-blocks/CU capacity (single round, no
// tail). r10's spill at cap 64 was this structure PLUS inline delta.

#if __has_builtin(__builtin_amdgcn_update_dpp)
#define HAVE_DPP 1
template<int CTRL, int RM>
__device__ __forceinline__ float updpp(float oldv, float src) {
    int r = __builtin_amdgcn_update_dpp(__builtin_bit_cast(int, oldv),
                                        __builtin_bit_cast(int, src),
                                        CTRL, RM, 0xF, false);
    return __builtin_bit_cast(float, r);
}
#else
#define HAVE_DPP 0
#endif

__global__ __launch_bounds__(512, 4) void k_scan(const float* __restrict__ xdbl,
                                                 const float* __restrict__ dlt,
                                                 const float* __restrict__ alogs,
                                                 const float* __restrict__ dsv_,
                                                 const float* __restrict__ xs,
                                                 float* __restrict__ ys) {
    int bid = blockIdx.x;
    int k = bid & 7;                 // XCD swizzle: k == XCD id
    int d = bid >> 3;
    int kd = k * D_ + d;
    int t = threadIdx.x;
    int lane = t & 63, wv = t >> 6;  // wv in 0..7
    int l0t = t * 8;

    __shared__ float An_s[16];
    __shared__ float agg_a[8][8], agg_b[8][8];
    __shared__ float cb_s[8][8];
    if (t < 16)
        An_s[t] = -expf(alogs[kd * N_ + t]);   // exp2-arg = d_l2 * An (ln2*log2e=1)

    float sA0, sA1, sA2, sA3, sA4, sA5, sA6, sA7;
    float sB0, sB1, sB2, sB3, sB4, sB5, sB6, sB7;
#define DECL(i) float d##i, u##i, y##i;
    REP8(DECL)
#undef DECL

    // ---- delta (precomputed, log2 domain) + u, both coalesced float4 ----
    {
        const float* dp = dlt + kd * L_ + l0t;
        const float4 da = *(const float4*)(dp);
        const float4 db = *(const float4*)(dp + 4);
        d0 = da.x; d1 = da.y; d2 = da.z; d3 = da.w;
        d4 = db.x; d5 = db.y; d6 = db.z; d7 = db.w;
        const float* up = xs + kd * L_ + l0t;
        const float4 ua = *(const float4*)(up);
        const float4 ub = *(const float4*)(up + 4);
        u0 = ua.x; u1 = ua.y; u2 = ua.z; u3 = ua.w;
        u4 = ub.x; u5 = ub.y; u6 = ub.z; u7 = ub.w;
    }
    const float dval = dsv_[kd];
#define UG(i) y##i = dval * u##i; u##i *= LN2F; u##i *= d##i;
    REP8(UG)
#undef UG

    __syncthreads();   // An_s ready

    const float* Bptr = xdbl + (k * CDBL + R_) * L_ + l0t;
    const float* Cptr = Bptr + N_ * L_;

#define PHA_E(i, Bc) { float e = EXP2(d##i * An); \
    rb = fmaf(e, rb, u##i * (Bc)); ra *= e; }
#define PHA(n, NOFF) { \
    const float An = An_s[(NOFF) + (n)]; \
    const float* Bn = Bptr + ((NOFF) + (n)) * L_; \
    const float4 b0 = *(const float4*)(Bn), b1 = *(const float4*)(Bn + 4); \
    float ra = 1.f, rb = 0.f; \
    PHA_E(0, b0.x) PHA_E(1, b0.y) PHA_E(2, b0.z) PHA_E(3, b0.w) \
    PHA_E(4, b1.x) PHA_E(5, b1.y) PHA_E(6, b1.z) PHA_E(7, b1.w) \
    sA##n = ra; sB##n = rb; }

#if HAVE_DPP
#define SSTAGE(CTRL, RM, n) { float pa = updpp<CTRL, RM>(1.f, sA##n); \
    float pb = updpp<CTRL, RM>(0.f, sB##n); \
    sB##n = fmaf(sA##n, pb, sB##n); sA##n *= pa; }
#define SSTAGE8(CTRL, RM) \
    SSTAGE(CTRL, RM, 0) SSTAGE(CTRL, RM, 1) SSTAGE(CTRL, RM, 2) SSTAGE(CTRL, RM, 3) \
    SSTAGE(CTRL, RM, 4) SSTAGE(CTRL, RM, 5) SSTAGE(CTRL, RM, 6) SSTAGE(CTRL, RM, 7)
#define PPREF(n) { \
    if (lane == 63) { agg_a[wv][n] = sA##n; agg_b[wv][n] = sB##n; } \
    sA##n = updpp<0x138, 0xF>(1.f, sA##n); \
    sB##n = updpp<0x138, 0xF>(0.f, sB##n); }
#define SCAN_CORE \
    SSTAGE8(0x111, 0xF) SSTAGE8(0x112, 0xF) SSTAGE8(0x114, 0xF) SSTAGE8(0x118, 0xF) \
    SSTAGE8(0x142, 0xA) SSTAGE8(0x143, 0xC) \
    REP8(PPREF)
#else
#define PBF(n) { float pa = __shfl_up(sA##n, off); float pb = __shfl_up(sB##n, off); \
    if (lane >= off) { sB##n = fmaf(sA##n, pb, sB##n); sA##n *= pa; } }
#define PPREF(n) { float ia = sA##n, ib = sB##n; \
    float ea = __shfl_up(ia, 1); float eb = __shfl_up(ib, 1); \
    if (lane == 0) { ea = 1.f; eb = 0.f; } \
    if (lane == 63) { agg_a[wv][n] = ia; agg_b[wv][n] = ib; } \
    sA##n = ea; sB##n = eb; }
#define SCAN_CORE \
    for (int off = 1; off < 64; off <<= 1) { REP8(PBF) } \
    REP8(PPREF)
#endif

#define PC(n) { sA##n = fmaf(sA##n, cb_s[wv][n], sB##n); }
#define SCAN_MID \
    SCAN_CORE \
    __syncthreads(); \
    if (t < 64) { int cw = t >> 3, cn = t & 7; float cb = 0.f; \
        for (int w2 = 0; w2 < cw; ++w2) \
            cb = fmaf(agg_a[w2][cn], cb, agg_b[w2][cn]); \
        cb_s[cw][cn] = cb; } \
    __syncthreads(); \
    REP8(PC)

#define PHD_E(i, Bc, Cc) { float e = EXP2(d##i * An); \
    h = fmaf(e, h, u##i * (Bc)); y##i = fmaf((Cc), h, y##i); }
#define PHD(n, NOFF) { \
    const float An = An_s[(NOFF) + (n)]; float h = sA##n; \
    const float* Bn = Bptr + ((NOFF) + (n)) * L_; \
    const float* Cn = Cptr + ((NOFF) + (n)) * L_; \
    const float4 b0 = *(const float4*)(Bn), b1 = *(const float4*)(Bn + 4); \
    const float4 c0 = *(const float4*)(Cn), c1 = *(const float4*)(Cn + 4); \
    PHD_E(0, b0.x, c0.x) PHD_E(1, b0.y, c0.y) PHD_E(2, b0.z, c0.z) PHD_E(3, b0.w, c0.w) \
    PHD_E(4, b1.x, c1.x) PHD_E(5, b1.y, c1.y) PHD_E(6, b1.z, c1.z) PHD_E(7, b1.w, c1.w) }

    // ======== group 0: n = 0..7 ========
    PHA(0, 0) PHA(1, 0) PHA(2, 0) PHA(3, 0) FENCE
    PHA(4, 0) PHA(5, 0) PHA(6, 0) PHA(7, 0) FENCE
    SCAN_MID
    PHD(0, 0) PHD(1, 0) FENCE
    PHD(2, 0) PHD(3, 0) FENCE
    PHD(4, 0) PHD(5, 0) FENCE
    PHD(6, 0) PHD(7, 0) FENCE

    // ======== group 1: n = 8..15 ========
    PHA(0, 8) PHA(1, 8) PHA(2, 8) PHA(3, 8) FENCE
    PHA(4, 8) PHA(5, 8) PHA(6, 8) PHA(7, 8) FENCE
    SCAN_MID
    PHD(0, 8) PHD(1, 8) FENCE
    PHD(2, 8) PHD(3, 8) FENCE
    PHD(4, 8) PHD(5, 8) FENCE
    PHD(6, 8) PHD(7, 8) FENCE

    float* yp = ys + kd * L_ + l0t;
    {
        float4 o;
        o.x = y0; o.y = y1; o.z = y2; o.w = y3; *(float4*)(yp + 0) = o;
        o.x = y4; o.y = y5; o.z = y6; o.w = y7; *(float4*)(yp + 4) = o;
    }
}

// ---------------- K3: cross_merge via LDS (per-d), ys -> ym[96][4096] --------
__global__ __launch_bounds__(512) void k_merge(const float* __restrict__ ys,
                                               float* __restrict__ ym) {
    __shared__ float buf[64 * 66];
    int d = blockIdx.x;
    int t = threadIdx.x;
    float a0 = 0.f, a1 = 0.f, a2 = 0.f, a3 = 0.f,
          a4 = 0.f, a5 = 0.f, a6 = 0.f, a7 = 0.f;
    #pragma unroll
    for (int k = 0; k < K_; ++k) {
        const float* srow = ys + (k * D_ + d) * L_;
        #pragma unroll
        for (int i = 0; i < 8; ++i) {
            int l = i * 512 + t;
            buf[PQ(l)] = srow[l];           // coalesced read
        }
        __syncthreads();
#define MACC(i) { int l = i * 512 + t; a##i += buf[PQ(merge_src(k, l))]; }
        REP8(MACC)
#undef MACC
        __syncthreads();
    }
    float* drow = ym + d * L_;
#define MST(i) drow[i * 512 + t] = a##i;
    REP8(MST)
#undef MST
}

// ---------------- K4: channel LayerNorm, ym[96][4096] -> out[4096][96] -------
__global__ __launch_bounds__(512) void k_ln(const float* __restrict__ ym,
                                            const float* __restrict__ gamma,
                                            const float* __restrict__ beta,
                                            float* __restrict__ out) {
    __shared__ float tile[D_ * 65];          // tile[d*65 + l_loc]
    __shared__ float pS[8][64], pQ[8][64];
    __shared__ float mu_s[64], rs_s[64];
    int t = threadIdx.x;
    int lb = blockIdx.x * 64;

    #pragma unroll
    for (int i = 0; i < 12; ++i) {
        int e = i * 512 + t;
        int dd = e >> 6, l_loc = e & 63;
        tile[dd * 65 + l_loc] = ym[dd * L_ + lb + l_loc];
    }
    __syncthreads();

    {
        int wgrp = t >> 6, l_loc = t & 63;
        float s = 0.f, sq = 0.f;
        #pragma unroll
        for (int j = 0; j < 12; ++j) {
            float v = tile[(wgrp * 12 + j) * 65 + l_loc];
            s += v; sq = fmaf(v, v, sq);
        }
        pS[wgrp][l_loc] = s; pQ[wgrp][l_loc] = sq;
    }
    __syncthreads();
    if (t < 64) {
        float s = 0.f, sq = 0.f;
        #pragma unroll
        for (int w2 = 0; w2 < 8; ++w2) { s += pS[w2][t]; sq += pQ[w2][t]; }
        float mu = s * (1.f / 96.f);
        float var = sq * (1.f / 96.f) - mu * mu;
        mu_s[t] = mu;
        rs_s[t] = rsqrtf(var + 1e-5f);
    }
    __syncthreads();

    #pragma unroll
    for (int i = 0; i < 12; ++i) {
        int e = i * 512 + t;
        int l_loc = e / 96, dd = e - l_loc * 96;
        float v = tile[dd * 65 + l_loc];
        float o = fmaf((v - mu_s[l_loc]) * rs_s[l_loc], gamma[dd], beta[dd]);
        out[lb * 96 + e] = o;
    }
}

extern "C" void kernel_launch(void* const* d_in, const int* in_sizes, int n_in,
                              void* d_out, int out_size, void* d_ws, size_t ws_size,
                              hipStream_t stream) {
    const float* x     = (const float*)d_in[0];
    const float* wproj = (const float*)d_in[1];
    const float* dtw   = (const float*)d_in[2];
    const float* dtb   = (const float*)d_in[3];
    const float* alogs = (const float*)d_in[4];
    const float* dsv   = (const float*)d_in[5];
    const float* gamma = (const float*)d_in[6];
    const float* beta  = (const float*)d_in[7];
    float* out = (float*)d_out;
    float* ws  = (float*)d_ws;

    float* xs   = ws;                 // 8*96*4096 floats (ys aliases: in-place)
    float* xdbl = ws + 3145728;       // 8*38*4096 floats
    float* dlt  = ws + 4390912;       // 8*96*4096 floats (delta, log2 domain)
    float* ym   = ws + 7536640;       // 96*4096 floats

    hipLaunchKernelGGL(k_xscan, dim3(96), dim3(512), 0, stream, x, xs);
    hipLaunchKernelGGL(k_xdbl, dim3(512), dim3(256), 0, stream, xs, wproj, xdbl);
    hipLaunchKernelGGL(k_delta, dim3(768), dim3(512), 0, stream,
                       xdbl, dtw, dtb, dlt);
    hipLaunchKernelGGL(k_scan, dim3(768), dim3(512), 0, stream,
                       xdbl, dlt, alogs, dsv, xs, xs /* ys in-place */);
    hipLaunchKernelGGL(k_merge, dim3(96), dim3(512), 0, stream, xs, ym);
    hipLaunchKernelGGL(k_ln, dim3(64), dim3(512), 0, stream, ym, gamma, beta, out);
}

// Round 13
// 89.021 us; speedup vs baseline: 1.4569x; 1.4569x over previous
//
#include <hip/hip_runtime.h>
#include <math.h>

#define D_ 96
#define L_ 4096
#define K_ 8
#define N_ 16
#define R_ 6
#define CDBL 38   // R + 2N
#define DL_ (D_ * L_)

#define REPN(M) M(0) M(1) M(2) M(3) M(4) M(5) M(6) M(7) \
                M(8) M(9) M(10) M(11) M(12) M(13) M(14) M(15)
#define REP8(M) M(0) M(1) M(2) M(3) M(4) M(5) M(6) M(7)
#define FENCE asm volatile("" ::: "memory");

#if __has_builtin(__builtin_amdgcn_exp2f)
#define EXP2(x) __builtin_amdgcn_exp2f(x)
#else
#define EXP2(x) exp2f(x)
#endif
#if __has_builtin(__builtin_amdgcn_logf)
#define LOG2F(x) __builtin_amdgcn_logf(x)
#else
#define LOG2F(x) __log2f(x)
#endif

#define LOG2E 1.44269504088896340736f
#define LN2F  0.69314718055994530942f

// source index within one channel's [64][64] image for direction k, flat pos l
__device__ __forceinline__ int src_index(int k, int l) {
    int h = l & 63, w = l >> 6;
    int lp = 4095 - l;
    int hp = lp & 63, wp = lp >> 6;
    switch (k) {
    case 0: return l;
    case 1: return (h << 6) + w;
    case 2: return lp;
    case 3: return (hp << 6) + wp;
    case 4: return (h << 6) + ((h + w) & 63);
    case 5: return (h << 6) + ((w - h) & 63);
    case 6: return (hp << 6) + ((hp + wp) & 63);
    default: return (hp << 6) + ((wp - hp) & 63);
    }
}

// inverse-permutation source for cross_merge (h = l>>6, w = l&63)
__device__ __forceinline__ int merge_src(int k, int l) {
    int h = l >> 6, w = l & 63;
    int i1 = (w << 6) + h;
    int i4 = (((w - h) & 63) << 6) + h;
    int i5 = (((w + h) & 63) << 6) + h;
    switch (k) {
    case 0: return l;
    case 1: return i1;
    case 2: return 4095 - l;
    case 3: return 4095 - i1;
    case 4: return i4;
    case 5: return i5;
    case 6: return 4095 - i4;
    default: return 4095 - i5;
    }
}

// padded LDS address for a [64][64] image tile (pad 66)
#define PQ(p) ((((p) >> 6) * 66) + ((p) & 63))

// ---------------- K0: cross-scan materialization x -> xs[8][96][4096] --------
__global__ __launch_bounds__(512) void k_xscan(const float* __restrict__ x,
                                               float* __restrict__ xs) {
    __shared__ float img[64 * 66];
    int d = blockIdx.x;
    int t = threadIdx.x;
    const float* xd = x + d * L_;
    #pragma unroll
    for (int i = 0; i < 8; ++i) {
        int l = i * 512 + t;
        img[PQ(l)] = xd[l];
    }
    __syncthreads();
    #pragma unroll
    for (int k = 0; k < K_; ++k) {
        float* dst = xs + (k * D_ + d) * L_;
        #pragma unroll
        for (int i = 0; i < 8; ++i) {
            int l = i * 512 + t;
            dst[l] = img[PQ(src_index(k, l))];
        }
    }
}

// ---------------- K1: x_dbl = wproj @ xs  (all-coalesced) --------------------
__global__ __launch_bounds__(256) void k_xdbl(const float* __restrict__ xs,
                                              const float* __restrict__ wproj,
                                              float* __restrict__ xdbl) {
    __shared__ float tile[64][100];
    int bid = blockIdx.x;
    int swz = (bid & 7) * 64 + (bid >> 3);   // XCD swizzle: each XCD owns one k
    int k = swz >> 6;
    int l0 = (swz & 63) * 64;

    const float* src = xs + k * DL_ + l0;
    for (int e = threadIdx.x; e < D_ * 64; e += 256) {
        int d = e >> 6, li = e & 63;
        tile[li][d] = src[d * L_ + li];     // coalesced
    }
    __syncthreads();

    int lt = threadIdx.x & 63;
    int cg = __builtin_amdgcn_readfirstlane(threadIdx.x >> 6);   // wave-uniform 0..3
    const float* wk = wproj + k * CDBL * D_;
    float acc[10];
    #pragma unroll
    for (int j = 0; j < 10; ++j) acc[j] = 0.f;
    for (int d4 = 0; d4 < D_; d4 += 4) {
        float4 tv = *(const float4*)&tile[lt][d4];
        #pragma unroll
        for (int j = 0; j < 10; ++j) {
            int c = cg + 4 * j;
            if (c < CDBL) {
                float4 wv = *(const float4*)&wk[c * D_ + d4];   // scalar -> s_load
                acc[j] = fmaf(tv.x, wv.x, acc[j]);
                acc[j] = fmaf(tv.y, wv.y, acc[j]);
                acc[j] = fmaf(tv.z, wv.z, acc[j]);
                acc[j] = fmaf(tv.w, wv.w, acc[j]);
            }
        }
    }
    #pragma unroll
    for (int j = 0; j < 10; ++j) {
        int c = cg + 4 * j;
        if (c < CDBL) xdbl[(k * CDBL + c) * L_ + l0 + lt] = acc[j];
    }
}

// ---------------- K2: fused delta + selective scan (round-8 proven) ----------
// EXACT round-8 structure (best measured: 46.6us, VGPR 72, zero spill at
// (512,3)): 512 threads, 8 elem/thread, grid 768, 16-n single pass with
// inline log2-domain delta, batched DPP scan, carry pre-stage, fences 4/2.
// One strictly-reducing edit vs r8: u loads coalesced from materialized xs.
// Lesson from r10/r12: the <=64-VGPR tier is unreachable (state needs ~70+);
// cap 85 via (512,3) is the stable point.

#if __has_builtin(__builtin_amdgcn_update_dpp)
#define HAVE_DPP 1
template<int CTRL, int RM>
__device__ __forceinline__ float updpp(float oldv, float src) {
    int r = __builtin_amdgcn_update_dpp(__builtin_bit_cast(int, oldv),
                                        __builtin_bit_cast(int, src),
                                        CTRL, RM, 0xF, false);
    return __builtin_bit_cast(float, r);
}
#else
#define HAVE_DPP 0
#endif

__global__ __launch_bounds__(512, 3) void k_scan(const float* __restrict__ xdbl,
                                                 const float* __restrict__ dtw,
                                                 const float* __restrict__ dtb,
                                                 const float* __restrict__ alogs,
                                                 const float* __restrict__ dsv_,
                                                 const float* __restrict__ xs,
                                                 float* __restrict__ ys) {
    int bid = blockIdx.x;
    int k = bid & 7;                 // XCD swizzle: k == XCD id
    int d = bid >> 3;
    int kd = k * D_ + d;
    int t = threadIdx.x;
    int lane = t & 63, wv = t >> 6;  // wv in 0..7
    int l0t = t * 8;

    __shared__ float An_s[16];
    __shared__ float agg_a[8][16], agg_b[8][16];
    __shared__ float cb_s[8][16];
    if (t < 16)
        An_s[t] = -expf(alogs[kd * N_ + t]);   // exp2-arg = d_l2 * An (ln2*log2e=1)

#define DECL(n) float sA##n, sB##n;
    REPN(DECL)
#undef DECL
#define DECL(i) float d##i, u##i, y##i;
    REP8(DECL)
#undef DECL

    // ---- delta (fused): 8 elements; d holds log2(1+e^s) ----
    const float* xr = xdbl + k * CDBL * L_;
    const float2* wp2 = (const float2*)(dtw + kd * R_);
    const float2 w01 = wp2[0], w23 = wp2[1], w45 = wp2[2];
    const float bias = dtb[kd];
    const float dval = dsv_[kd];
#define SPL2(dst, s) { float p = (s) * LOG2E; \
    float l2 = LOG2F(1.f + EXP2(p)); \
    dst = ((s) > 20.f) ? p : l2; }
#define DLTQ(j, i0, i1, i2, i3) { \
    const float4 r0 = *(const float4*)(xr + 0 * L_ + l0t + j * 4); \
    const float4 r1 = *(const float4*)(xr + 1 * L_ + l0t + j * 4); \
    const float4 r2 = *(const float4*)(xr + 2 * L_ + l0t + j * 4); \
    const float4 r3 = *(const float4*)(xr + 3 * L_ + l0t + j * 4); \
    const float4 r4 = *(const float4*)(xr + 4 * L_ + l0t + j * 4); \
    const float4 r5 = *(const float4*)(xr + 5 * L_ + l0t + j * 4); \
    float s; \
    s = fmaf(w01.x, r0.x, bias); s = fmaf(w01.y, r1.x, s); s = fmaf(w23.x, r2.x, s); \
    s = fmaf(w23.y, r3.x, s); s = fmaf(w45.x, r4.x, s); s = fmaf(w45.y, r5.x, s); \
    SPL2(d##i0, s) \
    s = fmaf(w01.x, r0.y, bias); s = fmaf(w01.y, r1.y, s); s = fmaf(w23.x, r2.y, s); \
    s = fmaf(w23.y, r3.y, s); s = fmaf(w45.x, r4.y, s); s = fmaf(w45.y, r5.y, s); \
    SPL2(d##i1, s) \
    s = fmaf(w01.x, r0.z, bias); s = fmaf(w01.y, r1.z, s); s = fmaf(w23.x, r2.z, s); \
    s = fmaf(w23.y, r3.z, s); s = fmaf(w45.x, r4.z, s); s = fmaf(w45.y, r5.z, s); \
    SPL2(d##i2, s) \
    s = fmaf(w01.x, r0.w, bias); s = fmaf(w01.y, r1.w, s); s = fmaf(w23.x, r2.w, s); \
    s = fmaf(w23.y, r3.w, s); s = fmaf(w45.x, r4.w, s); s = fmaf(w45.y, r5.w, s); \
    SPL2(d##i3, s) }
    DLTQ(0, 0, 1, 2, 3)
    DLTQ(1, 4, 5, 6, 7)
#undef DLTQ
#undef SPL2

    // ---- u from xs (coalesced float4; r13 edit); y = Ds*u; u -> delta*u ----
    {
        const float* up = xs + kd * L_ + l0t;
        const float4 ua = *(const float4*)(up);
        const float4 ub = *(const float4*)(up + 4);
        u0 = ua.x; u1 = ua.y; u2 = ua.z; u3 = ua.w;
        u4 = ub.x; u5 = ub.y; u6 = ub.z; u7 = ub.w;
    }
#define UG(i) y##i = dval * u##i; u##i *= LN2F; u##i *= d##i;
    REP8(UG)
#undef UG

    __syncthreads();   // An_s ready

    const float* Bptr = xdbl + (k * CDBL + R_) * L_ + l0t;
    const float* Cptr = Bptr + N_ * L_;

    // ---- Phase A: per-n local (a,b) segment aggregates ----
#define PHA_E(i, Bc) { float e = EXP2(d##i * An); \
    rb = fmaf(e, rb, u##i * (Bc)); ra *= e; }
#define PHA(n) { \
    const float An = An_s[n]; \
    const float* Bn = Bptr + n * L_; \
    const float4 b0 = *(const float4*)(Bn), b1 = *(const float4*)(Bn + 4); \
    float ra = 1.f, rb = 0.f; \
    PHA_E(0, b0.x) PHA_E(1, b0.y) PHA_E(2, b0.z) PHA_E(3, b0.w) \
    PHA_E(4, b1.x) PHA_E(5, b1.y) PHA_E(6, b1.z) PHA_E(7, b1.w) \
    sA##n = ra; sB##n = rb; }
    PHA(0) PHA(1) PHA(2) PHA(3) FENCE
    PHA(4) PHA(5) PHA(6) PHA(7) FENCE
    PHA(8) PHA(9) PHA(10) PHA(11) FENCE
    PHA(12) PHA(13) PHA(14) PHA(15) FENCE
#undef PHA
#undef PHA_E

    // ---- Phase B: 64-lane inclusive scan of 16 scalar (a,b) pairs ----
#if HAVE_DPP
#define SSTN(n) { float pa = updpp<SC_CTRL, SC_RM>(1.f, sA##n); \
                  float pb = updpp<SC_CTRL, SC_RM>(0.f, sB##n); \
                  sB##n = fmaf(sA##n, pb, sB##n); sA##n *= pa; }
#define SC_CTRL 0x111
#define SC_RM 0xF
    REPN(SSTN)            // row_shr:1
#undef SC_CTRL
#undef SC_RM
#define SC_CTRL 0x112
#define SC_RM 0xF
    REPN(SSTN)            // row_shr:2
#undef SC_CTRL
#undef SC_RM
#define SC_CTRL 0x114
#define SC_RM 0xF
    REPN(SSTN)            // row_shr:4
#undef SC_CTRL
#undef SC_RM
#define SC_CTRL 0x118
#define SC_RM 0xF
    REPN(SSTN)            // row_shr:8
#undef SC_CTRL
#undef SC_RM
#define SC_CTRL 0x142
#define SC_RM 0xA
    REPN(SSTN)            // row_bcast:15 -> rows 1,3
#undef SC_CTRL
#undef SC_RM
#define SC_CTRL 0x143
#define SC_RM 0xC
    REPN(SSTN)            // row_bcast:31 -> rows 2,3
#undef SC_CTRL
#undef SC_RM
#undef SSTN

    // exclusive prefix via DPP wave_shr:1 (lane0 keeps identity); store aggs
#define PPREF(n) { \
    if (lane == 63) { agg_a[wv][n] = sA##n; agg_b[wv][n] = sB##n; } \
    sA##n = updpp<0x138, 0xF>(1.f, sA##n); \
    sB##n = updpp<0x138, 0xF>(0.f, sB##n); }
    REPN(PPREF)
#undef PPREF
#else
#define PBF(n) { float pa = __shfl_up(sA##n, off); float pb = __shfl_up(sB##n, off); \
    if (lane >= off) { sB##n = fmaf(sA##n, pb, sB##n); sA##n *= pa; } }
    for (int off = 1; off < 64; off <<= 1) { REPN(PBF) }
#undef PBF
#define PPREF(n) { float ia = sA##n, ib = sB##n; \
    float ea = __shfl_up(ia, 1); float eb = __shfl_up(ib, 1); \
    if (lane == 0) { ea = 1.f; eb = 0.f; } \
    if (lane == 63) { agg_a[wv][n] = ia; agg_b[wv][n] = ib; } \
    sA##n = ea; sB##n = eb; }
    REPN(PPREF)
#undef PPREF
#endif
    __syncthreads();

    // ---- Phase C: carry pre-stage (128 threads), then 1 broadcast read/n ----
    if (t < 128) {
        int w = t >> 4, n = t & 15;
        float cb = 0.f;
        for (int w2 = 0; w2 < w; ++w2)
            cb = fmaf(agg_a[w2][n], cb, agg_b[w2][n]);
        cb_s[w][n] = cb;
    }
    __syncthreads();
#define PC(n) { sA##n = fmaf(sA##n, cb_s[wv][n], sB##n); }
    REPN(PC)
#undef PC

    // ---- Phase D: plain recurrence from h_enter; y += C*h ----
#define PHD_E(i, Bc, Cc) { float e = EXP2(d##i * An); \
    h = fmaf(e, h, u##i * (Bc)); y##i = fmaf((Cc), h, y##i); }
#define PHD(n) { \
    const float An = An_s[n]; float h = sA##n; \
    const float* Bn = Bptr + n * L_; const float* Cn = Cptr + n * L_; \
    const float4 b0 = *(const float4*)(Bn), b1 = *(const float4*)(Bn + 4); \
    const float4 c0 = *(const float4*)(Cn), c1 = *(const float4*)(Cn + 4); \
    PHD_E(0, b0.x, c0.x) PHD_E(1, b0.y, c0.y) PHD_E(2, b0.z, c0.z) PHD_E(3, b0.w, c0.w) \
    PHD_E(4, b1.x, c1.x) PHD_E(5, b1.y, c1.y) PHD_E(6, b1.z, c1.z) PHD_E(7, b1.w, c1.w) }
    PHD(0) PHD(1) FENCE
    PHD(2) PHD(3) FENCE
    PHD(4) PHD(5) FENCE
    PHD(6) PHD(7) FENCE
    PHD(8) PHD(9) FENCE
    PHD(10) PHD(11) FENCE
    PHD(12) PHD(13) FENCE
    PHD(14) PHD(15) FENCE
#undef PHD
#undef PHD_E

    float* yp = ys + kd * L_ + l0t;
    {
        float4 o;
        o.x = y0; o.y = y1; o.z = y2; o.w = y3; *(float4*)(yp + 0) = o;
        o.x = y4; o.y = y5; o.z = y6; o.w = y7; *(float4*)(yp + 4) = o;
    }
}

// ---------------- K3: cross_merge via LDS (per-d), ys -> ym[96][4096] --------
__global__ __launch_bounds__(512) void k_merge(const float* __restrict__ ys,
                                               float* __restrict__ ym) {
    __shared__ float buf[64 * 66];
    int d = blockIdx.x;
    int t = threadIdx.x;
    float a0 = 0.f, a1 = 0.f, a2 = 0.f, a3 = 0.f,
          a4 = 0.f, a5 = 0.f, a6 = 0.f, a7 = 0.f;
    #pragma unroll
    for (int k = 0; k < K_; ++k) {
        const float* srow = ys + (k * D_ + d) * L_;
        #pragma unroll
        for (int i = 0; i < 8; ++i) {
            int l = i * 512 + t;
            buf[PQ(l)] = srow[l];           // coalesced read
        }
        __syncthreads();
#define MACC(i) { int l = i * 512 + t; a##i += buf[PQ(merge_src(k, l))]; }
        REP8(MACC)
#undef MACC
        __syncthreads();
    }
    float* drow = ym + d * L_;
#define MST(i) drow[i * 512 + t] = a##i;
    REP8(MST)
#undef MST
}

// ---------------- K4: channel LayerNorm, ym[96][4096] -> out[4096][96] -------
__global__ __launch_bounds__(512) void k_ln(const float* __restrict__ ym,
                                            const float* __restrict__ gamma,
                                            const float* __restrict__ beta,
                                            float* __restrict__ out) {
    __shared__ float tile[D_ * 65];          // tile[d*65 + l_loc]
    __shared__ float pS[8][64], pQ[8][64];
    __shared__ float mu_s[64], rs_s[64];
    int t = threadIdx.x;
    int lb = blockIdx.x * 64;

    #pragma unroll
    for (int i = 0; i < 12; ++i) {
        int e = i * 512 + t;
        int dd = e >> 6, l_loc = e & 63;
        tile[dd * 65 + l_loc] = ym[dd * L_ + lb + l_loc];
    }
    __syncthreads();

    {
        int wgrp = t >> 6, l_loc = t & 63;
        float s = 0.f, sq = 0.f;
        #pragma unroll
        for (int j = 0; j < 12; ++j) {
            float v = tile[(wgrp * 12 + j) * 65 + l_loc];
            s += v; sq = fmaf(v, v, sq);
        }
        pS[wgrp][l_loc] = s; pQ[wgrp][l_loc] = sq;
    }
    __syncthreads();
    if (t < 64) {
        float s = 0.f, sq = 0.f;
        #pragma unroll
        for (int w2 = 0; w2 < 8; ++w2) { s += pS[w2][t]; sq += pQ[w2][t]; }
        float mu = s * (1.f / 96.f);
        float var = sq * (1.f / 96.f) - mu * mu;
        mu_s[t] = mu;
        rs_s[t] = rsqrtf(var + 1e-5f);
    }
    __syncthreads();

    #pragma unroll
    for (int i = 0; i < 12; ++i) {
        int e = i * 512 + t;
        int l_loc = e / 96, dd = e - l_loc * 96;
        float v = tile[dd * 65 + l_loc];
        float o = fmaf((v - mu_s[l_loc]) * rs_s[l_loc], gamma[dd], beta[dd]);
        out[lb * 96 + e] = o;
    }
}

extern "C" void kernel_launch(void* const* d_in, const int* in_sizes, int n_in,
                              void* d_out, int out_size, void* d_ws, size_t ws_size,
                              hipStream_t stream) {
    const float* x     = (const float*)d_in[0];
    const float* wproj = (const float*)d_in[1];
    const float* dtw   = (const float*)d_in[2];
    const float* dtb   = (const float*)d_in[3];
    const float* alogs = (const float*)d_in[4];
    const float* dsv   = (const float*)d_in[5];
    const float* gamma = (const float*)d_in[6];
    const float* beta  = (const float*)d_in[7];
    float* out = (float*)d_out;
    float* ws  = (float*)d_ws;

    float* xs   = ws;                 // 8*96*4096 floats (ys aliases: in-place)
    float* xdbl = ws + 3145728;       // 8*38*4096 floats
    float* ym   = ws + 4390912;       // 96*4096 floats

    hipLaunchKernelGGL(k_xscan, dim3(96), dim3(512), 0, stream, x, xs);
    hipLaunchKernelGGL(k_xdbl, dim3(512), dim3(256), 0, stream, xs, wproj, xdbl);
    hipLaunchKernelGGL(k_scan, dim3(768), dim3(512), 0, stream,
                       xdbl, dtw, dtb, alogs, dsv, xs, xs /* ys in-place */);
    hipLaunchKernelGGL(k_merge, dim3(96), dim3(512), 0, stream, xs, ym);
    hipLaunchKernelGGL(k_ln, dim3(64), dim3(512), 0, stream, ym, gamma, beta, out);
}